// Round 3
// baseline (1749.543 us; speedup 1.0000x reference)
//
#include <hip/hip_runtime.h>
#include <cstdint>

#define W 2048
#define H 512
// Split-array LDS layout, per buffer:
//   arrA: 2050 slots x 4 dwords (16B): {c01, c23, c45, c67}   -> hh0 b128 reads
//   arrB: 2050 slots x 2 dwords (8B):  {c89, x-pair}          -> hh1 b64 reads
// slot q holds position p = q-1 (ghost zero slots at q=0 and q=2049)
#define ABASE 0
#define BBASE (2050*4)
#define BUFD  (2050*4 + 2050*2)   // 12300 dwords per buffer

typedef __fp16 h2    __attribute__((ext_vector_type(2)));
typedef __fp16 f16x8 __attribute__((ext_vector_type(8)));
typedef float  f32x16 __attribute__((ext_vector_type(16)));

static __device__ __forceinline__ h2 as_h2(uint32_t u){ union{uint32_t u; h2 h;} x; x.u=u; return x.h; }
static __device__ __forceinline__ uint32_t as_u32(h2 h){ union{uint32_t u; h2 h;} x; x.h=h; return x.u; }

__global__ __launch_bounds__(1024, 1) void recurrent_kernel(
    const float* __restrict__ x,
    const float* __restrict__ w1, const float* __restrict__ b1,
    const float* __restrict__ w2, const float* __restrict__ b2,
    const float* __restrict__ wl, const float* __restrict__ bl,
    const float* __restrict__ wo, const float* __restrict__ bo,
    float* __restrict__ out)
{
    extern __shared__ uint32_t lds[];   // 2 x BUFD dwords, double-buffered rows
    const int tid  = threadIdx.x;
    const int b    = blockIdx.x;
    const int lane = tid & 63;
    const int wv   = tid >> 6;       // wave 0..15
    const int m    = lane & 31;      // MFMA: out-channel row / position col
    const int hh   = lane >> 5;      // k-group select

    for (int i = tid; i < 2*BUFD; i += 1024) lds[i] = 0;

    // ---- A fragments: weights resident in VGPRs for all 512 steps ----
    f16x8 afrag[3];
    #pragma unroll
    for (int tap = 0; tap < 3; ++tap)
        #pragma unroll
        for (int j = 0; j < 8; ++j) {
            int k = 8*hh + j;
            float v = (m < 10 && k < 12) ? wl[(m*12 + k)*3 + tap] : 0.f;
            afrag[tap][j] = (__fp16)v;
        }
    // 1x1-conv weight pairs matching this half-wave's D channels
    h2 wop0, wop1, wop2;
    if (hh == 0) {
        wop0 = __builtin_amdgcn_cvt_pkrtz(wo[0], wo[1]);
        wop1 = __builtin_amdgcn_cvt_pkrtz(wo[2], wo[3]);
        wop2 = __builtin_amdgcn_cvt_pkrtz(wo[8], wo[9]);
    } else {
        wop0 = __builtin_amdgcn_cvt_pkrtz(wo[4], wo[5]);
        wop1 = __builtin_amdgcn_cvt_pkrtz(wo[6], wo[7]);
        wop2 = __builtin_amdgcn_cvt_pkrtz(0.f, 0.f);
    }
    // bias preloaded into the accumulator (D rows 0..7 are the valid channels)
    f32x16 bias16;
    #pragma unroll
    for (int r = 0; r < 16; ++r) {
        int ch = (r & 3) + 8*(r >> 2) + 4*hh;
        bias16[r] = (r < 8 && ch < 10) ? bl[ch] : 0.f;
    }
    const float bov = bo[0];
    const int bpaddr = (lane ^ 32) << 2;
    const h2 hz = {(__fp16)0.f, (__fp16)0.f};

    const float* x1b = x + (((size_t)b*3 + 1)*H)*W;
    const float* x2b = x + (((size_t)b*3 + 2)*H)*W;
    float* outb = out + (size_t)b*H*W;

    // ---- hoisted per-lane constants for the hot loop ----
    const int base_n = wv*128 + m;                 // tile-0 column position
    const int rA_ = ABASE + 4*base_n;              // hh0 read base (dwords)
    const int rB_ = BBASE + 2*base_n;              // hh1 read base
    const int wA_ = ABASE + 4*(base_n + 1) + 2*hh; // arrA write base
    const int wB_ = BBASE + 2*(base_n + 1);        // arrB c89 write base (hh0)
    const int xw_ = BBASE + 2*(tid + 1) + 1;       // x-pair write base
    bool wok[4];
    #pragma unroll
    for (int ti = 0; ti < 4; ++ti) {
        int n = base_n + 32*ti;
        wok[ti] = (n != 0) && (n != W-1);
    }
    const int ocol0 = base_n + 64*hh;              // out cols handled by this lane
    const int ocol1 = ocol0 + 32;
    const float emul0 = (ocol0 == 0 || ocol0 == W-1) ? 0.f : 1.f;
    const float emul1 = (ocol1 == 0 || ocol1 == W-1) ? 0.f : 1.f;

    __syncthreads();   // LDS zeros visible before init writes

    // ---- init: row0 = relu(conv2('same', relu(conv1('valid', first_in)))) -> buf0 ----
    {
        const float* f0p = x + (((size_t)b*3 + 0)*H + (H-1))*W;  // x[b,0,-1,:]
        const float* f1p = x1b;                                   // x[b,1,0,:]
        const float* f2p = x2b;                                   // x[b,2,0,:]
        float fi[3][6];
        const int v0 = 2*tid - 1;      // first_in base position (w-2 of first output)
        #pragma unroll
        for (int l = 0; l < 6; ++l) {
            int v = v0 + l;
            bool ok = (v >= 0) && (v < W);
            fi[0][l] = ok ? f0p[v] : 0.f;
            fi[1][l] = ok ? f1p[v] : 0.f;
            fi[2][l] = ok ? f2p[v] : 0.f;
        }
        float h1v[5][4];
        #pragma unroll
        for (int c = 0; c < 5; ++c)
            #pragma unroll
            for (int i6 = 0; i6 < 4; ++i6) {
                int u = v0 + i6;               // h1 position, valid 0..2045 else 'same' pad 0
                float a = b1[c];
                #pragma unroll
                for (int j = 0; j < 3; ++j)
                    #pragma unroll
                    for (int k = 0; k < 3; ++k)
                        a += w1[(c*3 + j)*3 + k] * fi[j][i6 + k];
                h1v[c][i6] = (u >= 0 && u <= W-3) ? fmaxf(a, 0.f) : 0.f;
            }
        #pragma unroll
        for (int mm = 0; mm < 2; ++mm) {
            int w = 2*tid + 1 + mm;            // interior positions 1..2046
            if (w <= W - 2) {
                float h2c[10];
                #pragma unroll
                for (int c2 = 0; c2 < 10; ++c2) {
                    float a = b2[c2];
                    #pragma unroll
                    for (int c = 0; c < 5; ++c)
                        #pragma unroll
                        for (int k = 0; k < 3; ++k)
                            a += w2[(c2*5 + c)*3 + k] * h1v[c][mm + k];   // h1[w-2..w]
                    h2c[c2] = fmaxf(a, 0.f);
                }
                uint32_t* ra = lds + ABASE + 4*(w + 1);
                uint4 wr;
                wr.x = as_u32(__builtin_amdgcn_cvt_pkrtz(h2c[0], h2c[1]));
                wr.y = as_u32(__builtin_amdgcn_cvt_pkrtz(h2c[2], h2c[3]));
                wr.z = as_u32(__builtin_amdgcn_cvt_pkrtz(h2c[4], h2c[5]));
                wr.w = as_u32(__builtin_amdgcn_cvt_pkrtz(h2c[6], h2c[7]));
                *(uint4*)ra = wr;
                lds[BBASE + 2*(w + 1)] = as_u32(__builtin_amdgcn_cvt_pkrtz(h2c[8], h2c[9]));
            }
        }
        // x channels for step 1 -> buf0 (arrB dw1)
        #pragma unroll
        for (int i = 0; i < 2; ++i) {
            int p = tid + 1024*i;
            lds[BBASE + 2*(p + 1) + 1] = as_u32(__builtin_amdgcn_cvt_pkrtz(x1b[W + p], x2b[W + p]));
        }
    }
    __syncthreads();

    // ---- out[0] from row0 ----
    {
        h2 wo01 = __builtin_amdgcn_cvt_pkrtz(wo[0], wo[1]);
        h2 wo23 = __builtin_amdgcn_cvt_pkrtz(wo[2], wo[3]);
        h2 wo45 = __builtin_amdgcn_cvt_pkrtz(wo[4], wo[5]);
        h2 wo67 = __builtin_amdgcn_cvt_pkrtz(wo[6], wo[7]);
        h2 wo89 = __builtin_amdgcn_cvt_pkrtz(wo[8], wo[9]);
        #pragma unroll
        for (int i = 0; i < 2; ++i) {
            int p = 2*tid + i;
            const uint32_t* ra = lds + ABASE + 4*(p + 1);
            uint4 a = *(const uint4*)ra;               // c01,c23,c45,c67
            uint32_t e = lds[BBASE + 2*(p + 1)];       // c89
            float s = __builtin_amdgcn_fdot2(wo01, as_h2(a.x), bov, false);
            s = __builtin_amdgcn_fdot2(wo23, as_h2(a.y), s, false);
            s = __builtin_amdgcn_fdot2(wo45, as_h2(a.z), s, false);
            s = __builtin_amdgcn_fdot2(wo67, as_h2(a.w), s, false);
            s = __builtin_amdgcn_fdot2(wo89, as_h2(e),   s, false);
            outb[p] = s;
        }
    }

    // ---- recurrence: unrolled x2 (parity compile-time), all addresses reg+imm ----
    uint4 bu[4][3] = {};               // persistent; hh1 lanes' .zw stay 0 forever
    const float* xr1 = x1b + 2*W;      // uniform pointers -> SALU increments
    const float* xr2 = x2b + 2*W;
    float* op = outb + W;

#define STEP(RBX, WBX, PF, LAST) do {                                          \
    float xf1a, xf1b, xf2a, xf2b;                                              \
    if (PF) { xf1a = xr1[tid]; xf1b = xr1[tid + 1024];                         \
              xf2a = xr2[tid]; xf2b = xr2[tid + 1024]; }                       \
    if (hh == 0) {                                                             \
        _Pragma("unroll")                                                      \
        for (int ti = 0; ti < 4; ++ti) {                                       \
            _Pragma("unroll")                                                  \
            for (int tap = 0; tap < 3; ++tap)                                  \
                bu[ti][tap] = *(const uint4*)(lds + (RBX)*BUFD + rA_ + 128*ti + 4*tap); \
        }                                                                      \
    } else {                                                                   \
        _Pragma("unroll")                                                      \
        for (int ti = 0; ti < 4; ++ti) {                                       \
            _Pragma("unroll")                                                  \
            for (int tap = 0; tap < 3; ++tap) {                                \
                uint2 v = *(const uint2*)(lds + (RBX)*BUFD + rB_ + 64*ti + 2*tap); \
                bu[ti][tap].x = v.x; bu[ti][tap].y = v.y;                      \
            }                                                                  \
        }                                                                      \
    }                                                                          \
    float pv[4];                                                               \
    _Pragma("unroll")                                                          \
    for (int ti = 0; ti < 4; ++ti) {                                           \
        f32x16 acc = bias16;                                                   \
        _Pragma("unroll")                                                      \
        for (int tap = 0; tap < 3; ++tap) {                                    \
            union { uint4 u; f16x8 v; } c; c.u = bu[ti][tap];                  \
            acc = __builtin_amdgcn_mfma_f32_32x32x16_f16(afrag[tap], c.v, acc, 0, 0, 0); \
        }                                                                      \
        h2 p0 = __builtin_elementwise_max(__builtin_amdgcn_cvt_pkrtz(acc[0], acc[1]), hz); \
        h2 p1 = __builtin_elementwise_max(__builtin_amdgcn_cvt_pkrtz(acc[2], acc[3]), hz); \
        h2 p2 = __builtin_elementwise_max(__builtin_amdgcn_cvt_pkrtz(acc[4], acc[5]), hz); \
        if ((PF) && wok[ti]) {                                                 \
            uint2 wr; wr.x = as_u32(p0); wr.y = as_u32(p1);                    \
            *(uint2*)(lds + (WBX)*BUFD + wA_ + 128*ti) = wr;                   \
            if (hh == 0) lds[(WBX)*BUFD + wB_ + 64*ti] = as_u32(p2);           \
        }                                                                      \
        float pc = __builtin_amdgcn_fdot2(wop2, p2,                            \
                   __builtin_amdgcn_fdot2(wop1, p1,                            \
                   __builtin_amdgcn_fdot2(wop0, p0, 0.f, false), false), false); \
        int pi = __builtin_amdgcn_ds_bpermute(bpaddr, __builtin_bit_cast(int, pc)); \
        pv[ti] = pc + __builtin_bit_cast(float, pi);                           \
    }                                                                          \
    if (PF) {                                                                  \
        lds[(WBX)*BUFD + xw_]        = as_u32(__builtin_amdgcn_cvt_pkrtz(xf1a, xf2a)); \
        lds[(WBX)*BUFD + xw_ + 2048] = as_u32(__builtin_amdgcn_cvt_pkrtz(xf1b, xf2b)); \
    }                                                                          \
    if (!(LAST)) __syncthreads();                                              \
    {                                                                          \
        float pva = (hh == 0) ? pv[0] : pv[2];                                 \
        float pvb = (hh == 0) ? pv[1] : pv[3];                                 \
        op[ocol0] = fmaf(emul0, pva, bov);                                     \
        op[ocol1] = fmaf(emul1, pvb, bov);                                     \
        op += W;                                                               \
    }                                                                          \
    if (PF) { xr1 += W; xr2 += W; }                                            \
} while (0)

    #pragma unroll 1
    for (int t = 1; t < H - 1; t += 2) {
        STEP(0, 1, true, false);   // odd t:  read buf0, write buf1
        STEP(1, 0, true, false);   // even t: read buf1, write buf0
    }
    STEP(0, 1, false, true);       // t = H-1 = 511 (odd): read buf0, no row write
#undef STEP
}

extern "C" void kernel_launch(void* const* d_in, const int* in_sizes, int n_in,
                              void* d_out, int out_size, void* d_ws, size_t ws_size,
                              hipStream_t stream)
{
    const float* x  = (const float*)d_in[0];
    const float* w1 = (const float*)d_in[1];
    const float* b1 = (const float*)d_in[2];
    const float* w2 = (const float*)d_in[3];
    const float* b2 = (const float*)d_in[4];
    const float* wl = (const float*)d_in[5];
    const float* bl = (const float*)d_in[6];
    const float* wo = (const float*)d_in[7];
    const float* bo = (const float*)d_in[8];
    float* out = (float*)d_out;

    const int shbytes = 2 * BUFD * sizeof(uint32_t);   // 98.4 KB
    hipFuncSetAttribute((const void*)recurrent_kernel,
                        hipFuncAttributeMaxDynamicSharedMemorySize, shbytes);
    recurrent_kernel<<<8, 1024, shbytes, stream>>>(x, w1, b1, w2, b2, wl, bl, wo, bo, out);
}

// Round 5
// 893.712 us; speedup vs baseline: 1.9576x; 1.9576x over previous
//
#include <hip/hip_runtime.h>
#include <cstdint>

#define W 2048
#define H 512
// Split-array LDS layout, per buffer (both 16B/slot -> uniform full-exec b128 reads):
//   arrA: 2050 slots x 4 dwords: {c01, c23, c45, c67}      (hh0 fragment)
//   arrB: 2052 slots x 4 dwords: {c89, x-pair, 0, 0}       (hh1 fragment; pads stay 0)
// slot q holds position p = q-1 (ghost zero slots at q=0 and q=2049; +2 OOB pad slots in arrB)
#define ABASE 0
#define BBASE (2050*4)
#define BUFD  (2050*4 + 2052*4)   // 16408 dwords per buffer
#define NWAVE 16

typedef __fp16 h2    __attribute__((ext_vector_type(2)));
typedef __fp16 f16x8 __attribute__((ext_vector_type(8)));
typedef float  f32x16 __attribute__((ext_vector_type(16)));

static __device__ __forceinline__ h2 as_h2(uint32_t u){ union{uint32_t u; h2 h;} x; x.u=u; return x.h; }
static __device__ __forceinline__ uint32_t as_u32(h2 h){ union{uint32_t u; h2 h;} x; x.h=h; return x.u; }

__global__ __launch_bounds__(1024, 1) void recurrent_kernel(
    const float* __restrict__ x,
    const float* __restrict__ w1, const float* __restrict__ b1,
    const float* __restrict__ w2, const float* __restrict__ b2,
    const float* __restrict__ wl, const float* __restrict__ bl,
    const float* __restrict__ wo, const float* __restrict__ bo,
    float* __restrict__ out)
{
    extern __shared__ uint32_t lds[];   // 2 x BUFD dwords + NWAVE flags
    const int tid  = threadIdx.x;
    const int b    = blockIdx.x;
    const int lane = tid & 63;
    const int wv   = tid >> 6;       // wave 0..15
    const int m    = lane & 31;      // MFMA: out-channel row / position col
    const int hh   = lane >> 5;      // k-group select

    for (int i = tid; i < 2*BUFD + NWAVE; i += 1024) lds[i] = 0;

    // ---- A fragments: weights resident in VGPRs for all 512 steps ----
    // k = 8*hh + j ; channels 0-9 = prev row, 10-11 = x1,x2
    f16x8 afrag[3];
    #pragma unroll
    for (int tap = 0; tap < 3; ++tap)
        #pragma unroll
        for (int j = 0; j < 8; ++j) {
            int k = 8*hh + j;
            float v = (m < 10 && k < 12) ? wl[(m*12 + k)*3 + tap] : 0.f;
            afrag[tap][j] = (__fp16)v;
        }
    // 1x1-conv weight pairs matching this half-wave's D channels
    h2 wop0, wop1, wop2;
    if (hh == 0) {
        wop0 = __builtin_amdgcn_cvt_pkrtz(wo[0], wo[1]);
        wop1 = __builtin_amdgcn_cvt_pkrtz(wo[2], wo[3]);
        wop2 = __builtin_amdgcn_cvt_pkrtz(wo[8], wo[9]);
    } else {
        wop0 = __builtin_amdgcn_cvt_pkrtz(wo[4], wo[5]);
        wop1 = __builtin_amdgcn_cvt_pkrtz(wo[6], wo[7]);
        wop2 = __builtin_amdgcn_cvt_pkrtz(0.f, 0.f);
    }
    // bias preloaded as MFMA C-operand (D rows 0..7 are the valid channels)
    f32x16 bias16;
    #pragma unroll
    for (int r = 0; r < 16; ++r) {
        int ch = (r & 3) + 8*(r >> 2) + 4*hh;
        bias16[r] = (r < 8 && ch < 10) ? bl[ch] : 0.f;
    }
    const float bov = bo[0];
    const int bpaddr = (lane ^ 32) << 2;
    const h2 hz = {(__fp16)0.f, (__fp16)0.f};

    const float* x1b = x + (((size_t)b*3 + 1)*H)*W;
    const float* x2b = x + (((size_t)b*3 + 2)*H)*W;
    float* outb = out + (size_t)b*H*W;

    // hoisted per-lane index: identical stride/offset math for both halves
    const int base_n = wv*128 + m;
    const int rdi = (hh ? BBASE : ABASE) + 4*base_n;   // unified read base (dwords)
    uint32_t* fl = lds + 2*BUFD;
    const int na = (wv == 0)       ? wv : wv - 1;      // left neighbor (self at edge)
    const int nb = (wv == NWAVE-1) ? wv : wv + 1;      // right neighbor

    __syncthreads();   // LDS zeros (incl. flags, arrB pads) visible

    // ---- init: row0 = relu(conv2('same', relu(conv1('valid', first_in)))) -> buf0 ----
    {
        const float* f0p = x + (((size_t)b*3 + 0)*H + (H-1))*W;  // x[b,0,-1,:]
        const float* f1p = x1b;                                   // x[b,1,0,:]
        const float* f2p = x2b;                                   // x[b,2,0,:]
        float fi[3][6];
        const int v0 = 2*tid - 1;      // first_in base position (w-2 of first output)
        #pragma unroll
        for (int l = 0; l < 6; ++l) {
            int v = v0 + l;
            bool ok = (v >= 0) && (v < W);
            fi[0][l] = ok ? f0p[v] : 0.f;
            fi[1][l] = ok ? f1p[v] : 0.f;
            fi[2][l] = ok ? f2p[v] : 0.f;
        }
        float h1v[5][4];
        #pragma unroll
        for (int c = 0; c < 5; ++c)
            #pragma unroll
            for (int i6 = 0; i6 < 4; ++i6) {
                int u = v0 + i6;               // h1 position, valid 0..2045 else 'same' pad 0
                float a = b1[c];
                #pragma unroll
                for (int j = 0; j < 3; ++j)
                    #pragma unroll
                    for (int k = 0; k < 3; ++k)
                        a += w1[(c*3 + j)*3 + k] * fi[j][i6 + k];
                h1v[c][i6] = (u >= 0 && u <= W-3) ? fmaxf(a, 0.f) : 0.f;
            }
        #pragma unroll
        for (int mm = 0; mm < 2; ++mm) {
            int w = 2*tid + 1 + mm;            // interior positions 1..2046
            if (w <= W - 2) {
                float h2c[10];
                #pragma unroll
                for (int c2 = 0; c2 < 10; ++c2) {
                    float a = b2[c2];
                    #pragma unroll
                    for (int c = 0; c < 5; ++c)
                        #pragma unroll
                        for (int k = 0; k < 3; ++k)
                            a += w2[(c2*5 + c)*3 + k] * h1v[c][mm + k];   // h1[w-2..w]
                    h2c[c2] = fmaxf(a, 0.f);
                }
                uint32_t* ra = lds + ABASE + 4*(w + 1);
                uint4 wr;
                wr.x = as_u32(__builtin_amdgcn_cvt_pkrtz(h2c[0], h2c[1]));
                wr.y = as_u32(__builtin_amdgcn_cvt_pkrtz(h2c[2], h2c[3]));
                wr.z = as_u32(__builtin_amdgcn_cvt_pkrtz(h2c[4], h2c[5]));
                wr.w = as_u32(__builtin_amdgcn_cvt_pkrtz(h2c[6], h2c[7]));
                *(uint4*)ra = wr;
                lds[BBASE + 4*(w + 1)] = as_u32(__builtin_amdgcn_cvt_pkrtz(h2c[8], h2c[9]));
            }
        }
        // x channels for step 1 -> buf0 (arrB dw1); any mapping, barrier follows
        #pragma unroll
        for (int i = 0; i < 2; ++i) {
            int p = tid + 1024*i;
            lds[BBASE + 4*(p + 1) + 1] = as_u32(__builtin_amdgcn_cvt_pkrtz(x1b[W + p], x2b[W + p]));
        }
    }
    __syncthreads();   // the LAST block-wide barrier

    // ---- out[0] from row0 (reads only already-synced data) ----
    {
        h2 wo01 = __builtin_amdgcn_cvt_pkrtz(wo[0], wo[1]);
        h2 wo23 = __builtin_amdgcn_cvt_pkrtz(wo[2], wo[3]);
        h2 wo45 = __builtin_amdgcn_cvt_pkrtz(wo[4], wo[5]);
        h2 wo67 = __builtin_amdgcn_cvt_pkrtz(wo[6], wo[7]);
        h2 wo89 = __builtin_amdgcn_cvt_pkrtz(wo[8], wo[9]);
        #pragma unroll
        for (int i = 0; i < 2; ++i) {
            int p = 2*tid + i;
            const uint32_t* ra = lds + ABASE + 4*(p + 1);
            uint4 a = *(const uint4*)ra;               // c01,c23,c45,c67
            uint32_t e = lds[BBASE + 4*(p + 1)];       // c89
            float s = __builtin_amdgcn_fdot2(wo01, as_h2(a.x), bov, false);
            s = __builtin_amdgcn_fdot2(wo23, as_h2(a.y), s, false);
            s = __builtin_amdgcn_fdot2(wo45, as_h2(a.z), s, false);
            s = __builtin_amdgcn_fdot2(wo67, as_h2(a.w), s, false);
            s = __builtin_amdgcn_fdot2(wo89, as_h2(e),   s, false);
            outb[p] = s;
        }
    }

    // ---- recurrence: neighbor-gated wave pipeline, NO block-wide barriers ----
    // Protocol: wave w publishes fl[w]=t (RELEASE) after all step-t LDS writes.
    // Before step t's reads it requires fl[w±1] >= t-1 (ACQUIRE). Since a wave
    // publishes only after its reads, neighbor skew is bounded to 1 step ->
    // covers every RAW and WAR hazard on the double-buffered rows and x slots.
    #pragma unroll 1
    for (int t = 1; t < H; ++t) {
        const uint32_t* rb = lds + ((t - 1) & 1)*BUFD;   // row t-1 + x[t]
        uint32_t*       wb = lds + (t & 1)*BUFD;         // row t   + x[t+1]

        // global x[t+1] prefetch (wave-owned cols 128w..128w+127), issued before spin
        float xf1[2], xf2[2];
        const bool pf = (t + 1 < H);
        if (pf) {
            const float* r1 = x1b + (size_t)(t + 1)*W + 128*wv + lane;
            const float* r2 = x2b + (size_t)(t + 1)*W + 128*wv + lane;
            xf1[0] = r1[0];  xf1[1] = r1[64];
            xf2[0] = r2[0];  xf2[1] = r2[64];
        }

        // neighbor gate (uniform across the wave; acquire fences later LDS reads)
        if (t >= 2) {
            const uint32_t need = (uint32_t)(t - 1);
            while (__hip_atomic_load(&fl[na], __ATOMIC_ACQUIRE, __HIP_MEMORY_SCOPE_WORKGROUP) < need ||
                   __hip_atomic_load(&fl[nb], __ATOMIC_ACQUIRE, __HIP_MEMORY_SCOPE_WORKGROUP) < need)
                __builtin_amdgcn_s_sleep(1);
        }

        // phase A: 12 uniform full-exec b128 reads (shared vaddr + imm offsets)
        uint4 bu[4][3];
        #pragma unroll
        for (int ti = 0; ti < 4; ++ti)
            #pragma unroll
            for (int tap = 0; tap < 3; ++tap)
                bu[ti][tap] = *(const uint4*)(rb + rdi + 128*ti + 4*tap);

        uint32_t stash[4][3];
        float pv[4];
        #pragma unroll
        for (int ti = 0; ti < 4; ++ti) {
            union { uint4 u; f16x8 v; } c0, c1, c2;
            c0.u = bu[ti][0]; c1.u = bu[ti][1]; c2.u = bu[ti][2];
            f32x16 acc = __builtin_amdgcn_mfma_f32_32x32x16_f16(afrag[0], c0.v, bias16, 0, 0, 0);
            acc = __builtin_amdgcn_mfma_f32_32x32x16_f16(afrag[1], c1.v, acc, 0, 0, 0);
            acc = __builtin_amdgcn_mfma_f32_32x32x16_f16(afrag[2], c2.v, acc, 0, 0, 0);
            h2 p0 = __builtin_elementwise_max(__builtin_amdgcn_cvt_pkrtz(acc[0], acc[1]), hz);
            h2 p1 = __builtin_elementwise_max(__builtin_amdgcn_cvt_pkrtz(acc[2], acc[3]), hz);
            h2 p2 = __builtin_elementwise_max(__builtin_amdgcn_cvt_pkrtz(acc[4], acc[5]), hz);
            stash[ti][0] = as_u32(p0); stash[ti][1] = as_u32(p1); stash[ti][2] = as_u32(p2);
            // fused 1x1 conv: this half's channels + other half via bpermute
            float pc = __builtin_amdgcn_fdot2(wop2, p2,
                       __builtin_amdgcn_fdot2(wop1, p1,
                       __builtin_amdgcn_fdot2(wop0, p0, 0.f, false), false), false);
            int pi = __builtin_amdgcn_ds_bpermute(bpaddr, __builtin_bit_cast(int, pc));
            pv[ti] = pc + __builtin_bit_cast(float, pi);
        }

        // phase B: write row t into wb
        // hh0: c0-3 (arrA dw0-1) + c8,9 (arrB dw0); hh1: c4-7 (arrA dw2-3)
        #pragma unroll
        for (int ti = 0; ti < 4; ++ti) {
            const int n = base_n + 32*ti;
            if (n != 0 && n != W-1) {
                uint32_t* rp = wb + ABASE + 4*(n + 1) + 2*hh;
                uint2 wr; wr.x = stash[ti][0]; wr.y = stash[ti][1];
                *(uint2*)rp = wr;
                if (hh == 0) wb[BBASE + 4*(n + 1)] = stash[ti][2];
            }
        }
        if (pf) {
            const int p0 = 128*wv + lane;
            wb[BBASE + 4*(p0 + 1) + 1]      = as_u32(__builtin_amdgcn_cvt_pkrtz(xf1[0], xf2[0]));
            wb[BBASE + 4*(p0 + 64 + 1) + 1] = as_u32(__builtin_amdgcn_cvt_pkrtz(xf1[1], xf2[1]));
        }

        // release-publish step t (fences the wave's prior LDS writes)
        if (lane == 0)
            __hip_atomic_store(&fl[wv], (uint32_t)t, __ATOMIC_RELEASE, __HIP_MEMORY_SCOPE_WORKGROUP);

        // out-store (global, no LDS dep; overlaps neighbors' progress)
        #pragma unroll
        for (int i = 0; i < 2; ++i) {
            const int ti = 2*hh + i;
            const int n = base_n + 32*ti;
            float val = (n == 0 || n == W-1) ? bov : pv[ti] + bov;
            outb[(size_t)t*W + n] = val;
        }
    }
}

extern "C" void kernel_launch(void* const* d_in, const int* in_sizes, int n_in,
                              void* d_out, int out_size, void* d_ws, size_t ws_size,
                              hipStream_t stream)
{
    const float* x  = (const float*)d_in[0];
    const float* w1 = (const float*)d_in[1];
    const float* b1 = (const float*)d_in[2];
    const float* w2 = (const float*)d_in[3];
    const float* b2 = (const float*)d_in[4];
    const float* wl = (const float*)d_in[5];
    const float* bl = (const float*)d_in[6];
    const float* wo = (const float*)d_in[7];
    const float* bo = (const float*)d_in[8];
    float* out = (float*)d_out;

    const int shbytes = (2 * BUFD + NWAVE) * sizeof(uint32_t);   // ~128.3 KB
    hipFuncSetAttribute((const void*)recurrent_kernel,
                        hipFuncAttributeMaxDynamicSharedMemorySize, shbytes);
    recurrent_kernel<<<8, 1024, shbytes, stream>>>(x, w1, b1, w2, b2, wl, bl, wo, bo, out);
}